// Round 9
// baseline (1296.185 us; speedup 1.0000x reference)
//
#include <hip/hip_runtime.h>
#include <hip/hip_bf16.h>
#include <stdint.h>

#define C_DIM 32
#define T_DIM 2048
#define EMBED 1024
#define HEADS 16
#define MAP   4096
#define NROWS (C_DIM * T_DIM)   // 65536 token rows
#define MCHUNK 16384            // MLP M-chunk (4 chunks)

typedef float  f32x4  __attribute__((ext_vector_type(4)));
typedef __bf16 bf16x8 __attribute__((ext_vector_type(8)));

__device__ __forceinline__ float bf2f(__hip_bfloat16 b) { return __bfloat162float(b); }
__device__ __forceinline__ __hip_bfloat16 f2bf(float f) { return __float2bfloat16(f); }

// async global->LDS, 16B per lane. LDS dest must be WAVE-UNIFORM base; HW adds lane*16.
__device__ __forceinline__ void gload_lds16(const void* g, void* l) {
  __builtin_amdgcn_global_load_lds(
      (const __attribute__((address_space(1))) void*)g,
      (__attribute__((address_space(3))) void*)l,
      16, 0, 0);
}

// ---------------- precompute kernels for fused MLP ----------------
// MLP has NO nonlinearity: out = z@(fc2*fc1)^T + (fc2@fc1_b + fc2_b).

// transpose fc1_w [4096][1024] f32 -> f1T hi/lo bf16 [1024][4096]
__global__ __launch_bounds__(256) void tsplit_k(const float* __restrict__ src,
                                                __hip_bfloat16* __restrict__ th,
                                                __hip_bfloat16* __restrict__ tl) {
  __shared__ float tile[64][65];
  int bm = blockIdx.x >> 4;     // 64 row-tiles over 4096
  int bn = blockIdx.x & 15;     // 16 col-tiles over 1024
  int t = threadIdx.x;
  #pragma unroll
  for (int j = 0; j < 16; j++) {
    int idx = j * 256 + t;      // 0..4095
    int r = idx >> 6, c = idx & 63;
    tile[r][c] = src[(size_t)(bm * 64 + r) * 1024 + bn * 64 + c];
  }
  __syncthreads();
  #pragma unroll
  for (int j = 0; j < 16; j++) {
    int idx = j * 256 + t;
    int c = idx >> 6, r = idx & 63;   // out-row = src col, out-col = src row
    float v = tile[r][c];
    __hip_bfloat16 hi = f2bf(v);
    float lo = v - bf2f(hi);
    size_t o = (size_t)(bn * 64 + c) * 4096 + bm * 64 + r;
    th[o] = hi; tl[o] = f2bf(lo);
  }
}

// elementwise split f32 -> bf16 hi + bf16 lo (lo = x - hi)
__global__ void split_k(const float* __restrict__ src, __hip_bfloat16* __restrict__ hi,
                        __hip_bfloat16* __restrict__ lo, int n4) {
  int i = blockIdx.x * 256 + threadIdx.x;
  if (i < n4) {
    float4 v = ((const float4*)src)[i];
    union { __hip_bfloat16 h[4]; uint2 u; } ph, pl;
    float vv[4] = { v.x, v.y, v.z, v.w };
    #pragma unroll
    for (int j = 0; j < 4; j++) {
      ph.h[j] = f2bf(vv[j]);
      pl.h[j] = f2bf(vv[j] - bf2f(ph.h[j]));
    }
    *(uint2*)&hi[i * 4] = ph.u;
    *(uint2*)&lo[i * 4] = pl.u;
  }
}

// cbias[e] = sum_m fc2_w[e][m]*fc1_b[m] + fc2_b[e]   (fp32)
__global__ __launch_bounds__(256) void cbias_k(const float* __restrict__ fc2w,
                                               const float* __restrict__ b1,
                                               const float* __restrict__ b2,
                                               float* __restrict__ cb) {
  int wid = threadIdx.x >> 6, lane = threadIdx.x & 63;
  int e = blockIdx.x * 4 + wid;   // grid 256 -> e 0..1023
  const float* row = fc2w + (size_t)e * 4096;
  float s = 0.f;
  #pragma unroll 8
  for (int m = lane; m < 4096; m += 64) s += row[m] * b1[m];
  #pragma unroll
  for (int off = 1; off < 64; off <<= 1) s += __shfl_xor(s, off);
  if (lane == 0) cb[e] = s + b2[e];
}

// ---------------- attention prep (unchanged structure) ----------------

// Mt[o][d] = sum_j wq[j][d]*wk[j][o]   (diag = x^T M x == q.k)
__global__ void mt_k(const float* __restrict__ wq, const float* __restrict__ wk,
                     __hip_bfloat16* __restrict__ Mt) {
  int i = blockIdx.x * 256 + threadIdx.x;  // 4096 = o*64+d
  int o = i >> 6, d = i & 63;
  float s = 0.f;
  #pragma unroll
  for (int j = 0; j < 64; j++) s += wq[j * 64 + d] * wk[j * 64 + o];
  Mt[i] = f2bf(s);
}

// xsum[c][e] = sum_t inp[c][t][e]  (two-stage, deterministic)
__global__ void xsum_part_k(const float* __restrict__ inp, float* __restrict__ part) {
  int bid = blockIdx.x;                       // 2048 = c(32) * chunk(16) * eq(4)
  int eq = bid & 3, chunk = (bid >> 2) & 15, c = bid >> 6;
  int e = eq * 256 + threadIdx.x;
  const float* p = inp + ((size_t)c * 2048 + chunk * 128) * 1024 + e;
  float s = 0.f;
  #pragma unroll 8
  for (int t = 0; t < 128; t++) s += p[(size_t)t * 1024];
  part[((size_t)c * 16 + chunk) * 1024 + e] = s;
}

__global__ void xsum_reduce_k(const float* __restrict__ part, float* __restrict__ xsum) {
  int i = blockIdx.x * 256 + threadIdx.x;     // 32768
  int c = i >> 10, e = i & 1023;
  float s = 0.f;
  #pragma unroll
  for (int k = 0; k < 16; k++) s += part[((size_t)c * 16 + k) * 1024 + e];
  xsum[i] = s;
}

// vsum[c][h][o] = sum_d xsum[c][h*64+d] * wv[o][d]
__global__ void vsum_k(const float* __restrict__ xsum, const float* __restrict__ wv,
                       float* __restrict__ vsum) {
  int i = blockIdx.x * 256 + threadIdx.x;     // 32768 = (c*16+h)*64+o
  int o = i & 63, ch = i >> 6;
  const float* xr = xsum + ch * 64;
  const float* wr = wv + o * 64;
  float s = 0.f;
  #pragma unroll
  for (int d = 0; d < 64; d++) s += xr[d] * wr[d];
  vsum[i] = s;
}

// diag = x^T Mt^T x via MFMA. X = inp viewed [NRH,64]; 256 rows/block, 4 waves.
__global__ __launch_bounds__(256) void diag_k(const float* __restrict__ inp,
                                              const __hip_bfloat16* __restrict__ Mt,
                                              float* __restrict__ diag) {
  __shared__ __align__(16) __hip_bfloat16 Xs[256][72];  // +8 pad
  __shared__ __align__(16) __hip_bfloat16 Ms[64][72];
  int tid = threadIdx.x, lane = tid & 63, wid = tid >> 6;
  size_t rbase = (size_t)blockIdx.x * 256;
  const float* xb = inp + rbase * 64;
  #pragma unroll 4
  for (int j = 0; j < 16; j++) {
    int g = j * 1024 + tid * 4;
    float4 v = *(const float4*)&xb[g];
    int row = g >> 6, col = g & 63;
    union { __hip_bfloat16 h[4]; uint2 u; } pk;
    pk.h[0] = f2bf(v.x); pk.h[1] = f2bf(v.y); pk.h[2] = f2bf(v.z); pk.h[3] = f2bf(v.w);
    *(uint2*)&Xs[row][col] = pk.u;
  }
  #pragma unroll 4
  for (int j = 0; j < 16; j++) {
    int idx = j * 256 + tid;
    Ms[idx >> 6][idx & 63] = Mt[idx];
  }
  __syncthreads();

  int lrow = lane & 15, lk8 = (lane >> 4) << 3;
  f32x4 acc[4][4] = {};
  #pragma unroll
  for (int ks = 0; ks < 2; ks++) {
    bf16x8 a[4], b[4];
    #pragma unroll
    for (int mi = 0; mi < 4; mi++)
      a[mi] = *(const bf16x8*)&Xs[wid * 64 + mi * 16 + lrow][ks * 32 + lk8];
    #pragma unroll
    for (int ni = 0; ni < 4; ni++)
      b[ni] = *(const bf16x8*)&Ms[ni * 16 + lrow][ks * 32 + lk8];
    #pragma unroll
    for (int mi = 0; mi < 4; mi++)
      #pragma unroll
      for (int ni = 0; ni < 4; ni++)
        acc[mi][ni] = __builtin_amdgcn_mfma_f32_16x16x32_bf16(a[mi], b[ni], acc[mi][ni], 0, 0, 0);
  }
  // diag[row] = sum_o U[row][o]*X[row][o]; U frag: col=lane&15, row=(lane>>4)*4+i
  #pragma unroll
  for (int mi = 0; mi < 4; mi++) {
    #pragma unroll
    for (int i = 0; i < 4; i++) {
      int row = wid * 64 + mi * 16 + ((lane >> 4) << 2) + i;
      float s = 0.f;
      #pragma unroll
      for (int ni = 0; ni < 4; ni++) {
        int o = ni * 16 + lrow;
        s += acc[mi][ni][i] * bf2f(Xs[row][o]);
      }
      s += __shfl_xor(s, 1); s += __shfl_xor(s, 2);
      s += __shfl_xor(s, 4); s += __shfl_xor(s, 8);
      if (lrow == 0) diag[rbase + row] = s * 0.03125f;  // 1/sqrt(1024)
    }
  }
}

// softmax over C per (t,h); diag layout [c][t][h] linear, wbuf [(t*16+h)][c]
__global__ void softmax_k(const float* __restrict__ diag, float* __restrict__ wbuf) {
  int i = blockIdx.x * 256 + threadIdx.x;  // 32768 = t*16+h
  float v[32];
  float mx = -1e30f;
  #pragma unroll
  for (int c = 0; c < 32; c++) { v[c] = diag[(size_t)c * 32768 + i]; mx = fmaxf(mx, v[c]); }
  float sum = 0.f;
  #pragma unroll
  for (int c = 0; c < 32; c++) { v[c] = __expf(v[c] - mx); sum += v[c]; }
  float inv = 1.f / sum;
  #pragma unroll
  for (int c = 0; c < 32; c++) wbuf[(size_t)i * 32 + c] = v[c] * inv;
}

// x2 = inp + w*vsum; n1 = LN(x2); z = x2+n1 -> split bf16 hi/lo (chunk-local)
__global__ __launch_bounds__(256) void rowfuse_k(const float* __restrict__ inp,
                                                 const float* __restrict__ wbuf,
                                                 const float* __restrict__ vsum,
                                                 const float* __restrict__ g1,
                                                 const float* __restrict__ b1,
                                                 __hip_bfloat16* __restrict__ zh,
                                                 __hip_bfloat16* __restrict__ zl,
                                                 int rbase) {
  int rl = blockIdx.x;
  int r = rbase + rl;
  int c = r >> 11, t = r & 2047;
  int tid = threadIdx.x, lane = tid & 63, wid = tid >> 6;
  int e = tid * 4, h = tid >> 4, d = e & 63;
  float4 xi = *(const float4*)&inp[(size_t)r * 1024 + e];
  float w = wbuf[(size_t)(t * 16 + h) * 32 + c];
  float4 vs = *(const float4*)&vsum[(c * 16 + h) * 64 + d];
  float x2[4] = { xi.x + w * vs.x, xi.y + w * vs.y, xi.z + w * vs.z, xi.w + w * vs.w };
  float s = x2[0] + x2[1] + x2[2] + x2[3];
  float q = x2[0]*x2[0] + x2[1]*x2[1] + x2[2]*x2[2] + x2[3]*x2[3];
  #pragma unroll
  for (int off = 1; off < 64; off <<= 1) { s += __shfl_xor(s, off); q += __shfl_xor(q, off); }
  __shared__ float ls[4], lq[4];
  if (lane == 0) { ls[wid] = s; lq[wid] = q; }
  __syncthreads();
  s = ls[0] + ls[1] + ls[2] + ls[3];
  q = lq[0] + lq[1] + lq[2] + lq[3];
  float mu = s * (1.f / 1024.f);
  float var = q * (1.f / 1024.f) - mu * mu;
  float rs = rsqrtf(var + 1e-5f);
  union { __hip_bfloat16 hh[4]; uint2 u; } ph, pl;
  #pragma unroll
  for (int j = 0; j < 4; j++) {
    float n1 = (x2[j] - mu) * rs * g1[e + j] + b1[e + j];
    float z = x2[j] + n1;
    ph.hh[j] = f2bf(z);
    pl.hh[j] = f2bf(z - bf2f(ph.hh[j]));
  }
  *(uint2*)&zh[(size_t)rl * 1024 + e] = ph.u;
  *(uint2*)&zl[(size_t)rl * 1024 + e] = pl.u;
}

// ------- 128x128 split-bf16 GEMM: C = (Ah+Al)[M,K] * ((Bh+Bl)[N,K])^T + bias -------
// m97 2-barrier structure; 3-MFMA split product (hh + lh + hl), fp32 out.
template <int ADD_BIAS>
__global__ __launch_bounds__(256) void gemm_split(const __hip_bfloat16* __restrict__ Ah,
                                                  const __hip_bfloat16* __restrict__ Al,
                                                  const __hip_bfloat16* __restrict__ Bh,
                                                  const __hip_bfloat16* __restrict__ Bl,
                                                  const float* __restrict__ bias,
                                                  float* __restrict__ C, int M, int N, int K) {
  __shared__ __align__(16) __hip_bfloat16 Ash[128 * 32];
  __shared__ __align__(16) __hip_bfloat16 Asl[128 * 32];
  __shared__ __align__(16) __hip_bfloat16 Bsh[128 * 32];
  __shared__ __align__(16) __hip_bfloat16 Bsl[128 * 32];
  int nbn = N >> 7;
  int lg = 31 - __clz(nbn);                 // nbn power of two (8 here)
  int nwg = gridDim.x;
  int wg = blockIdx.x;
  int cpx = nwg >> 3;                       // grids %8==0 (64 / 1024)
  int swz = (wg & 7) * cpx + (wg >> 3);     // XCD-contiguous remap (bijective)
  int bm = swz >> lg, bn = swz & (nbn - 1);

  int tid = threadIdx.x;
  int lane = tid & 63;
  int wid = tid >> 6;
  int lrow = lane & 15;
  int lk8 = (lane >> 4) << 3;

  const __hip_bfloat16* Abh = Ah + (size_t)bm * 128 * K;
  const __hip_bfloat16* Abl = Al + (size_t)bm * 128 * K;
  const __hip_bfloat16* Bbh = Bh + (size_t)bn * 128 * K;
  const __hip_bfloat16* Bbl = Bl + (size_t)bn * 128 * K;

  f32x4 acc[4][4] = {};
  int wr = (wid >> 1) << 6;
  int wc = (wid & 1) << 6;

  for (int k0 = 0; k0 < K; k0 += 32) {
    #pragma unroll
    for (int is = 0; is < 2; ++is) {
      int chunk = is * 256 + tid;           // 0..511, 16B each
      int row = chunk >> 2;
      int kk = (chunk & 3) << 3;
      size_t goff = (size_t)row * K + (k0 + kk);
      int lbase = (is * 256 + (wid << 6)) * 8;   // wave-uniform
      gload_lds16(Abh + goff, &Ash[lbase]);
      gload_lds16(Abl + goff, &Asl[lbase]);
      gload_lds16(Bbh + goff, &Bsh[lbase]);
      gload_lds16(Bbl + goff, &Bsl[lbase]);
    }
    __syncthreads();  // drains vmcnt(0): staged data visible
    bf16x8 bh[4], bl[4];
    #pragma unroll
    for (int ni = 0; ni < 4; ni++) {
      bh[ni] = *(const bf16x8*)&Bsh[(wc + ni * 16 + lrow) * 32 + lk8];
      bl[ni] = *(const bf16x8*)&Bsl[(wc + ni * 16 + lrow) * 32 + lk8];
    }
    #pragma unroll
    for (int mi = 0; mi < 4; mi++) {
      bf16x8 ah = *(const bf16x8*)&Ash[(wr + mi * 16 + lrow) * 32 + lk8];
      bf16x8 al = *(const bf16x8*)&Asl[(wr + mi * 16 + lrow) * 32 + lk8];
      #pragma unroll
      for (int ni = 0; ni < 4; ni++) {
        acc[mi][ni] = __builtin_amdgcn_mfma_f32_16x16x32_bf16(ah, bh[ni], acc[mi][ni], 0, 0, 0);
        acc[mi][ni] = __builtin_amdgcn_mfma_f32_16x16x32_bf16(al, bh[ni], acc[mi][ni], 0, 0, 0);
        acc[mi][ni] = __builtin_amdgcn_mfma_f32_16x16x32_bf16(ah, bl[ni], acc[mi][ni], 0, 0, 0);
      }
    }
    __syncthreads();  // all reads done before next stage overwrites
  }

  int r0 = bm * 128 + wr + ((lane >> 4) << 2);
  int c0 = bn * 128 + wc + lrow;
  #pragma unroll
  for (int ni = 0; ni < 4; ni++) {
    int col = c0 + ni * 16;
    float bv = ADD_BIAS ? bias[col] : 0.f;
    #pragma unroll
    for (int mi = 0; mi < 4; mi++) {
      #pragma unroll
      for (int i = 0; i < 4; i++) {
        int row = r0 + mi * 16 + i;
        C[(size_t)row * N + col] = acc[mi][ni][i] + bv;
      }
    }
  }
}

// final LN in-place on d_out rows
__global__ __launch_bounds__(256) void ln_out_k(float* __restrict__ out,
                                                const float* __restrict__ g2,
                                                const float* __restrict__ b2) {
  int r = blockIdx.x;
  int tid = threadIdx.x, lane = tid & 63, wid = tid >> 6;
  int e = tid * 4;
  float4 v = *(const float4*)&out[(size_t)r * 1024 + e];
  float x[4] = { v.x, v.y, v.z, v.w };
  float s = x[0] + x[1] + x[2] + x[3];
  float q = x[0]*x[0] + x[1]*x[1] + x[2]*x[2] + x[3]*x[3];
  #pragma unroll
  for (int off = 1; off < 64; off <<= 1) { s += __shfl_xor(s, off); q += __shfl_xor(q, off); }
  __shared__ float ls[4], lq[4];
  if (lane == 0) { ls[wid] = s; lq[wid] = q; }
  __syncthreads();
  s = ls[0] + ls[1] + ls[2] + ls[3];
  q = lq[0] + lq[1] + lq[2] + lq[3];
  float mu = s * (1.f / 1024.f);
  float var = q * (1.f / 1024.f) - mu * mu;
  float rs = rsqrtf(var + 1e-5f);
  float4 o;
  o.x = (x[0] - mu) * rs * g2[e + 0] + b2[e + 0];
  o.y = (x[1] - mu) * rs * g2[e + 1] + b2[e + 1];
  o.z = (x[2] - mu) * rs * g2[e + 2] + b2[e + 2];
  o.w = (x[3] - mu) * rs * g2[e + 3] + b2[e + 3];
  *(float4*)&out[(size_t)r * 1024 + e] = o;
}

extern "C" void kernel_launch(void* const* d_in, const int* in_sizes, int n_in,
                              void* d_out, int out_size, void* d_ws, size_t ws_size,
                              hipStream_t stream) {
  const float* inp   = (const float*)d_in[0];
  const float* wq    = (const float*)d_in[1];
  const float* wk    = (const float*)d_in[2];
  const float* wv    = (const float*)d_in[3];
  const float* ln1_g = (const float*)d_in[4];
  const float* ln1_b = (const float*)d_in[5];
  const float* fc1_w = (const float*)d_in[6];
  const float* fc1_b = (const float*)d_in[7];
  const float* fc2_w = (const float*)d_in[8];
  const float* fc2_b = (const float*)d_in[9];
  const float* ln2_g = (const float*)d_in[10];
  const float* ln2_b = (const float*)d_in[11];
  float* out = (float*)d_out;

  // workspace layout (~115 MiB total)
  const long long MB = 1ll << 20;
  char* ws = (char*)d_ws;
  __hip_bfloat16* zh   = (__hip_bfloat16*)(ws);                 // 32 MiB (MCHUNK x 1024)
  __hip_bfloat16* zl   = (__hip_bfloat16*)(ws + 32 * MB);       // 32 MiB
  __hip_bfloat16* f1Th = (__hip_bfloat16*)(ws + 64 * MB);       // 8 MiB (1024x4096)
  __hip_bfloat16* f1Tl = (__hip_bfloat16*)(ws + 72 * MB);       // 8 MiB
  __hip_bfloat16* fc2h = (__hip_bfloat16*)(ws + 80 * MB);       // 8 MiB
  __hip_bfloat16* fc2l = (__hip_bfloat16*)(ws + 88 * MB);       // 8 MiB
  float* Wcomb         = (float*)(ws + 96 * MB);                // 4 MiB (1024x1024)
  __hip_bfloat16* Wch  = (__hip_bfloat16*)(ws + 100 * MB);      // 2 MiB
  __hip_bfloat16* Wcl  = (__hip_bfloat16*)(ws + 102 * MB);      // 2 MiB
  float* diag          = (float*)(ws + 104 * MB);               // 4 MiB
  float* wbuf          = (float*)(ws + 108 * MB);               // 4 MiB
  float* part          = (float*)(ws + 112 * MB);               // 2 MiB
  float* xsum          = (float*)(ws + 114 * MB);               // 128 KiB
  float* vsum          = (float*)(ws + 114 * MB + 131072);      // 128 KiB
  __hip_bfloat16* Mt   = (__hip_bfloat16*)(ws + 114 * MB + 262144); // 8 KiB
  float* cbias         = (float*)(ws + 114 * MB + 270336);      // 4 KiB
  (void)ws_size; (void)in_sizes; (void)n_in; (void)out_size;

  // fused-MLP precompute: Wcomb = fc2_w @ fc1_w (split-bf16, fp32 accum)
  tsplit_k<<<1024, 256, 0, stream>>>(fc1_w, f1Th, f1Tl);
  split_k<<<4096, 256, 0, stream>>>(fc2_w, fc2h, fc2l, 1048576);
  gemm_split<0><<<64, 256, 0, stream>>>(fc2h, fc2l, f1Th, f1Tl, nullptr, Wcomb, 1024, 1024, 4096);
  split_k<<<1024, 256, 0, stream>>>(Wcomb, Wch, Wcl, 262144);
  cbias_k<<<256, 256, 0, stream>>>(fc2_w, fc1_b, fc2_b, cbias);

  // attention path
  mt_k<<<16, 256, 0, stream>>>(wq, wk, Mt);
  xsum_part_k<<<2048, 256, 0, stream>>>(inp, part);
  xsum_reduce_k<<<128, 256, 0, stream>>>(part, xsum);
  vsum_k<<<128, 256, 0, stream>>>(xsum, wv, vsum);
  diag_k<<<4096, 256, 0, stream>>>(inp, Mt, diag);
  softmax_k<<<128, 256, 0, stream>>>(diag, wbuf);

  // fused MLP main: out = z @ Wcomb^T + cbias  (split-bf16, 137 GF logical)
  for (int ch = 0; ch < NROWS / MCHUNK; ch++) {
    rowfuse_k<<<MCHUNK, 256, 0, stream>>>(inp, wbuf, vsum, ln1_g, ln1_b, zh, zl, ch * MCHUNK);
    gemm_split<1><<<(MCHUNK / 128) * (EMBED / 128), 256, 0, stream>>>(
        zh, zl, Wch, Wcl, cbias, out + (size_t)ch * MCHUNK * EMBED, MCHUNK, EMBED, EMBED);
  }
  ln_out_k<<<65536, 256, 0, stream>>>(out, ln2_g, ln2_b);
}